// Round 2
// baseline (63.005 us; speedup 1.0000x reference)
//
#include <hip/hip_runtime.h>

// HONU order-2, L=64: out[i] = b + sum_{j<=k} W[woff(j)+k-j] * x[i,j] * x[i,k]
// woff(j) = 64j - j(j-1)/2  (lex order of combinations_with_replacement)
//
// R3: unified wave code. Previous version had 16 fully-unrolled per-wave
// template cases (~28 KB straight-line code, every instruction executed
// exactly once per wave -> I-fetch latency exposed on a 1-block/CU grid).
// Now all 16 waves execute ONE shared 4x64 masked loop:
//   wave s handles j in {4s..4s+3}; inner k runs the full 0..63 with the
//   triangular bound applied as a SCALAR select (k>=j is wave-uniform since
//   s goes through readfirstlane), so W loads stay s_load (SGPR base +
//   constant offsets) and the mask costs SALU only (parallel pipe).
// Dynamic FMAs 134 -> 256 per lane (still ~0.85us/SIMD, far under budget);
// code ~28 KB -> ~4 KB shared by all waves.

#define ROWS 64
#define XSTRIDE 65  // +1 pad: LDS bank = (65*lane + k)%32 = (lane+k)%32 -> 2-way, free

__global__ __launch_bounds__(1024, 4) void honu_kernel(
    const float* __restrict__ X, const float* __restrict__ W,
    const float* __restrict__ Bias, float* __restrict__ out, int nrows) {
  __shared__ float tile[ROWS * XSTRIDE];  // 16.6 KB
  __shared__ float part[16][64];          // 4 KB

  const int tid = threadIdx.x;
  const int lane = tid & 63;
  const int row0 = blockIdx.x * ROWS;

  // Coalesced staging: thread tid loads float4 #tid of the 64x64 tile.
  {
    const int r = tid >> 4;         // row within tile
    const int c = (tid & 15) << 2;  // starting col
    float4 v = make_float4(0.f, 0.f, 0.f, 0.f);
    if (row0 + r < nrows) {
      v = reinterpret_cast<const float4*>(X)[(size_t)(row0 + r) * 16 +
                                             (tid & 15)];
    }
    float* dst = &tile[r * XSTRIDE + c];
    dst[0] = v.x;
    dst[1] = v.y;
    dst[2] = v.z;
    dst[3] = v.w;
  }
  __syncthreads();

  const float* xrow = &tile[lane * XSTRIDE];

  // Whole row in registers; compile-time indices only (no scratch).
  float x[64];
#pragma unroll
  for (int k = 0; k < 64; ++k) x[k] = xrow[k];

  // Wave id via readfirstlane -> compiler-provably uniform -> scalar W path.
  const int s = __builtin_amdgcn_readfirstlane(tid >> 6);

  float acc = 0.0f;
#pragma unroll
  for (int jj = 0; jj < 4; ++jj) {
    const int j = 4 * s + jj;                       // uniform, SALU
    const int base2 = 63 * j - (j * (j - 1)) / 2;   // woff(j) - j
    float y = 0.0f;
#pragma unroll
    for (int k = 0; k < 64; ++k) {
      // Unconditional load (always in-bounds: base2+k <= 2079 < 2145),
      // then a wave-uniform select -> s_cmp + s_cselect, SALU pipe.
      const float wv = W[base2 + k];
      const float w = (k >= j) ? wv : 0.0f;
      y = __builtin_fmaf(w, x[k], y);
    }
    // x[j] with runtime j would scratch the register array -> read from LDS.
    acc = __builtin_fmaf(xrow[j], y, acc);
  }

  part[tid >> 6][lane] = acc;
  __syncthreads();

  if (tid < 64) {
    const int orow = row0 + tid;
    if (orow < nrows) {
      float r = Bias[0];
#pragma unroll
      for (int w = 0; w < 16; ++w) r += part[w][tid];
      out[orow] = r;
    }
  }
}

extern "C" void kernel_launch(void* const* d_in, const int* in_sizes, int n_in,
                              void* d_out, int out_size, void* d_ws,
                              size_t ws_size, hipStream_t stream) {
  const float* X = (const float*)d_in[0];     // (16384, 64) fp32
  const float* W = (const float*)d_in[1];     // (2145,) fp32 (first 2080 used)
  const float* Bias = (const float*)d_in[2];  // (1,) fp32
  float* out = (float*)d_out;                 // (16384,) fp32

  const int nrows = out_size;  // 16384
  const int grid = (nrows + ROWS - 1) / ROWS;
  honu_kernel<<<grid, 1024, 0, stream>>>(X, W, Bias, out, nrows);
}